// Round 1
// baseline (840.037 us; speedup 1.0000x reference)
//
#include <hip/hip_runtime.h>
#include <hip/hip_bf16.h>

typedef __attribute__((ext_vector_type(4))) float f32x4;
typedef __attribute__((ext_vector_type(8))) short short8;
typedef __attribute__((ext_vector_type(4))) short short4v;

#define B_   32
#define S_   2048
#define H_   1024
#define D2_  2048   // 2H
#define M_   65536  // S*B rows of the uk GEMM
#define BM   128
#define BN   128
#define BK   32
#define LDK  40     // padded LDS row length in shorts (80 B stride, 16B-aligned)

// RNE f32 -> bf16
__device__ __forceinline__ short f2bf(float f) {
  unsigned u = __float_as_uint(f);
  u = (u + 0x7fffu + ((u >> 16) & 1u)) >> 16;
  return (short)u;
}

// tanh via hardware exp2: tanh(x) = 1 - 2/(2^(2x*log2e)+1). Correct limits at +-inf.
__device__ __forceinline__ float fast_tanh(float x) {
  float e = __builtin_amdgcn_exp2f(x * 2.885390081777927f);
  return 1.0f - 2.0f * __builtin_amdgcn_rcpf(e + 1.0f);
}

// ---------------- kernel 1: Ua_w f32 -> bf16 ----------------
__global__ void k_convert_ua(const float* __restrict__ src, short* __restrict__ dst) {
  int i = (blockIdx.x * 256 + threadIdx.x) * 4;
  f32x4 v = *(const f32x4*)(src + i);
  short4v o;
  o.x = f2bf(v.x); o.y = f2bf(v.y); o.z = f2bf(v.z); o.w = f2bf(v.w);
  *(short4v*)(dst + i) = o;
}

// ---------------- kernel 2: wqb[b][h] = q[b] . Wa_w[h] + Wa_b[h] + Ua_b[h] ----------------
__global__ void k_wq(const float* __restrict__ query, const float* __restrict__ Wa_w,
                     const float* __restrict__ Wa_b, const float* __restrict__ Ua_b,
                     float* __restrict__ wqb) {
  int b = blockIdx.x;
  int t = threadIdx.x;
  __shared__ float q[H_];
  for (int i = t; i < H_; i += 256) q[i] = query[(size_t)b * (4 * H_) + 3 * H_ + i];
  __syncthreads();
  for (int h = t; h < H_; h += 256) {
    const float* wr = Wa_w + (size_t)h * H_;
    float acc = 0.f;
    for (int k = 0; k < H_; k += 4) {
      f32x4 wv = *(const f32x4*)(wr + k);
      acc += wv.x * q[k] + wv.y * q[k + 1] + wv.z * q[k + 2] + wv.w * q[k + 3];
    }
    wqb[b * H_ + h] = acc + Wa_b[h] + Ua_b[h];
  }
}

// ---------------- kernel 3: fused GEMM (keys @ Ua^T) + tanh + Va-reduce -> score partials ----------------
// A = keys viewed as [65536][2048] f32 (row r = s*32 + b), staged f32->bf16 in LDS.
// B = Ua_w bf16 [1024][2048] (NT gemm: both K-contiguous).
// scores_p[r*16 + nt*2 + wn] = sum over this col-tile-half of Va[h]*tanh(wqb[b][h] + uk[r][h])
__global__ __launch_bounds__(256) void k_gemm_score(
    const float* __restrict__ keys, const short* __restrict__ uab,
    const float* __restrict__ wqb, const float* __restrict__ va,
    float* __restrict__ scores_p) {
  __shared__ short As[BM * LDK];
  __shared__ short Bs[BN * LDK];
  const int nt = blockIdx.x;   // 0..7  (fast: the 8 blocks sharing an A tile co-schedule)
  const int mt = blockIdx.y;   // 0..511
  const int r0 = mt * BM;
  const int h0 = nt * BN;
  const int t = threadIdx.x;
  const int lane = t & 63;
  const int w = t >> 6;
  const int wm = w >> 1;       // 0..1 : row half
  const int wn = w & 1;        // 0..1 : col half

  f32x4 acc[4][4] = {};

  const int arr = t >> 3;          // A: 0..31 rows per issue
  const int akq = (t & 7) * 4;     // A: f32 col
  const int brr = t >> 2;          // B: 0..63 rows per issue
  const int bkq = (t & 3) * 8;     // B: bf16 col

  for (int k0 = 0; k0 < D2_; k0 += BK) {
    __syncthreads();
    // stage A tile (128 x 32 f32 -> bf16)
    #pragma unroll
    for (int is = 0; is < 4; ++is) {
      int row = is * 32 + arr;
      f32x4 v = *(const f32x4*)(keys + (size_t)(r0 + row) * D2_ + k0 + akq);
      short4v o;
      o.x = f2bf(v.x); o.y = f2bf(v.y); o.z = f2bf(v.z); o.w = f2bf(v.w);
      *(short4v*)&As[row * LDK + akq] = o;
    }
    // stage B tile (128 x 32 bf16 copy)
    #pragma unroll
    for (int is = 0; is < 2; ++is) {
      int row = is * 64 + brr;
      short8 v = *(const short8*)(uab + (size_t)(h0 + row) * D2_ + k0 + bkq);
      *(short8*)&Bs[row * LDK + bkq] = v;
    }
    __syncthreads();
    // fragments + MFMA
    const int lrow = lane & 15;
    const int lk = (lane >> 4) * 8;
    short8 af[4], bfr[4];
    #pragma unroll
    for (int m = 0; m < 4; ++m)
      af[m] = *(const short8*)&As[(wm * 64 + m * 16 + lrow) * LDK + lk];
    #pragma unroll
    for (int n = 0; n < 4; ++n)
      bfr[n] = *(const short8*)&Bs[(wn * 64 + n * 16 + lrow) * LDK + lk];
    #pragma unroll
    for (int m = 0; m < 4; ++m)
      #pragma unroll
      for (int n = 0; n < 4; ++n)
        acc[m][n] = __builtin_amdgcn_mfma_f32_16x16x32_bf16(af[m], bfr[n], acc[m][n], 0, 0, 0);
  }

  // epilogue: tanh + Va-weighted row-reduce.
  // C/D layout (m89-verified): col = lane&15, row = (lane>>4)*4 + reg
  const int lgrp = lane >> 4;
  const int lc = lane & 15;
  float vah[4];
  #pragma unroll
  for (int n = 0; n < 4; ++n) vah[n] = va[h0 + wn * 64 + n * 16 + lc];
  #pragma unroll
  for (int m = 0; m < 4; ++m) {
    #pragma unroll
    for (int reg = 0; reg < 4; ++reg) {
      int row = wm * 64 + m * 16 + lgrp * 4 + reg;
      int r = r0 + row;
      int bb = r & (B_ - 1);     // r = s*32 + b
      float s = 0.f;
      #pragma unroll
      for (int n = 0; n < 4; ++n) {
        int h = h0 + wn * 64 + n * 16 + lc;
        float valv = acc[m][n][reg] + wqb[bb * H_ + h];
        s += vah[n] * fast_tanh(valv);
      }
      s += __shfl_xor(s, 1);
      s += __shfl_xor(s, 2);
      s += __shfl_xor(s, 4);
      s += __shfl_xor(s, 8);
      if (lc == 0) scores_p[(size_t)r * 16 + nt * 2 + wn] = s;
    }
  }
}

// ---------------- kernel 4: reduce partials + softmax -> weights ----------------
__global__ void k_softmax(const float* __restrict__ scores_p, float* __restrict__ out) {
  int b = blockIdx.x;
  int t = threadIdx.x;
  __shared__ float sc[S_];
  __shared__ float red[4];
  float lmax = -3.4e38f;
  #pragma unroll
  for (int i = 0; i < 8; ++i) {
    int s = t + i * 256;
    const float* p = scores_p + ((size_t)s * B_ + b) * 16;  // one 64B line
    float v = 0.f;
    #pragma unroll
    for (int j = 0; j < 16; ++j) v += p[j];
    sc[s] = v;
    lmax = fmaxf(lmax, v);
  }
  #pragma unroll
  for (int o = 32; o >= 1; o >>= 1) lmax = fmaxf(lmax, __shfl_xor(lmax, o));
  if ((t & 63) == 0) red[t >> 6] = lmax;
  __syncthreads();
  float gmax = fmaxf(fmaxf(red[0], red[1]), fmaxf(red[2], red[3]));
  __syncthreads();
  float lsum = 0.f;
  #pragma unroll
  for (int i = 0; i < 8; ++i) {
    int s = t + i * 256;
    float e = __builtin_amdgcn_exp2f((sc[s] - gmax) * 1.4426950408889634f);
    sc[s] = e;
    lsum += e;
  }
  #pragma unroll
  for (int o = 32; o >= 1; o >>= 1) lsum += __shfl_xor(lsum, o);
  if ((t & 63) == 0) red[t >> 6] = lsum;
  __syncthreads();
  float inv = 1.0f / (red[0] + red[1] + red[2] + red[3]);
  for (int i = 0; i < 8; ++i) {
    int s = t + i * 256;
    out[(size_t)65536 + b * S_ + s] = sc[s] * inv;
  }
}

// ---------------- kernel 5: context partials: cp[sc][b][d] = sum_{s in chunk} w[b][s]*keys[s][b][d] ----------------
__global__ void k_ctx_partial(const float* __restrict__ keys, const float* __restrict__ wts,
                              float* __restrict__ cp) {
  int b = blockIdx.x;    // 32
  int dc = blockIdx.y;   // 2
  int scn = blockIdx.z;  // 8
  int t = threadIdx.x;
  __shared__ float wl[256];
  int s0 = scn * 256;
  wl[t] = wts[b * S_ + s0 + t];
  __syncthreads();
  int d = dc * 1024 + t * 4;
  f32x4 acc = {};
  #pragma unroll 4
  for (int i = 0; i < 256; ++i) {
    int s = s0 + i;
    f32x4 kv = *(const f32x4*)(keys + ((size_t)s * B_ + b) * D2_ + d);
    acc += kv * wl[i];
  }
  *(f32x4*)(cp + ((size_t)scn * B_ + b) * D2_ + d) = acc;
}

// ---------------- kernel 6: reduce context partials ----------------
__global__ void k_ctx_reduce(const float* __restrict__ cp, float* __restrict__ out) {
  int i = blockIdx.x * 256 + threadIdx.x;
  float s = 0.f;
  #pragma unroll
  for (int j = 0; j < 8; ++j) s += cp[(size_t)j * 65536 + i];
  out[i] = s;
}

extern "C" void kernel_launch(void* const* d_in, const int* in_sizes, int n_in,
                              void* d_out, int out_size, void* d_ws, size_t ws_size,
                              hipStream_t stream) {
  const float* query = (const float*)d_in[0];
  const float* keys  = (const float*)d_in[1];
  const float* Wa_w  = (const float*)d_in[2];
  const float* Wa_b  = (const float*)d_in[3];
  const float* Ua_w  = (const float*)d_in[4];
  const float* Ua_b  = (const float*)d_in[5];
  const float* Va_w  = (const float*)d_in[6];
  // Va_b (d_in[7]) intentionally unused: softmax is shift-invariant.
  float* out = (float*)d_out;

  char* ws = (char*)d_ws;
  short* uab = (short*)(ws);                                   // 4 MB bf16 Ua_w
  float* wqb = (float*)(ws + 4u * 1024 * 1024);                // 128 KB
  float* sp  = (float*)(ws + 4u * 1024 * 1024 + 128 * 1024);   // 4 MB score partials
  float* cp  = (float*)(ws + 8u * 1024 * 1024 + 128 * 1024 + 128 * 1024); // 2 MB ctx partials

  hipLaunchKernelGGL(k_convert_ua, dim3(2048), dim3(256), 0, stream, Ua_w, uab);
  hipLaunchKernelGGL(k_wq, dim3(32), dim3(256), 0, stream, query, Wa_w, Wa_b, Ua_b, wqb);
  hipLaunchKernelGGL(k_gemm_score, dim3(8, 512), dim3(256), 0, stream, keys, uab, wqb, Va_w, sp);
  hipLaunchKernelGGL(k_softmax, dim3(32), dim3(256), 0, stream, sp, out);
  hipLaunchKernelGGL(k_ctx_partial, dim3(32, 2, 8), dim3(256), 0, stream, keys, out + 65536, cp);
  hipLaunchKernelGGL(k_ctx_reduce, dim3(256), dim3(256), 0, stream, cp, out);
}

// Round 2
// 699.560 us; speedup vs baseline: 1.2008x; 1.2008x over previous
//
#include <hip/hip_runtime.h>
#include <hip/hip_bf16.h>

typedef __attribute__((ext_vector_type(4))) float f32x4;
typedef __attribute__((ext_vector_type(8))) short short8;

#define B_   32
#define S_   2048
#define H_   1024
#define D2_  2048   // 2H
#define BM   128
#define BN   512
#define BK   32
#define NKS  64     // D2_/BK

// RNE f32 -> bf16
__device__ __forceinline__ short f2bf(float f) {
  unsigned u = __float_as_uint(f);
  u = (u + 0x7fffu + ((u >> 16) & 1u)) >> 16;
  return (short)u;
}

__device__ __forceinline__ short8 cvt8(f32x4 a, f32x4 b) {
  short8 o;
  o[0] = f2bf(a.x); o[1] = f2bf(a.y); o[2] = f2bf(a.z); o[3] = f2bf(a.w);
  o[4] = f2bf(b.x); o[5] = f2bf(b.y); o[6] = f2bf(b.z); o[7] = f2bf(b.w);
  return o;
}

// tanh via hardware exp2: tanh(x) = 1 - 2/(2^(2x*log2e)+1). Correct limits at +-inf.
__device__ __forceinline__ float fast_tanh(float x) {
  float e = __builtin_amdgcn_exp2f(x * 2.885390081777927f);
  return 1.0f - 2.0f * __builtin_amdgcn_rcpf(e + 1.0f);
}

__device__ __forceinline__ void gload16(const short* g, short* l) {
  __builtin_amdgcn_global_load_lds((const __attribute__((address_space(1))) void*)g,
                                   (__attribute__((address_space(3))) void*)l, 16, 0, 0);
}

// ---------------- kernel 1: Ua_w f32 -> bf16, tiled [nt(2)][kt(64)] of [512][32] shorts,
// internally XOR-swizzled: 16B-quarter slot q' holds source k-quarter q = q' ^ (row&3).
__global__ void k_convert_ua(const float* __restrict__ src, short* __restrict__ dst) {
  int idx = blockIdx.x * 256 + threadIdx.x;   // one 16B block each; 262144 total
  int b16 = idx & 2047;                        // within-tile 16B index
  int kt  = (idx >> 11) & 63;
  int nt  = idx >> 17;
  int row = b16 >> 2;                          // 0..511 (h within tile)
  int q   = (b16 & 3) ^ (row & 3);             // source k-quarter
  const float* s = src + ((size_t)(nt * 512 + row)) * D2_ + kt * 32 + q * 8;
  f32x4 a = *(const f32x4*)s;
  f32x4 b = *(const f32x4*)(s + 4);
  *(short8*)(dst + (size_t)idx * 8) = cvt8(a, b);
}

// ---------------- kernel 2: wqb[b][h] = q[b] . Wa_w[h] + Wa_b[h] + Ua_b[h] ----------------
__global__ void k_wq(const float* __restrict__ query, const float* __restrict__ Wa_w,
                     const float* __restrict__ Wa_b, const float* __restrict__ Ua_b,
                     float* __restrict__ wqb) {
  int b = blockIdx.x;
  int t = threadIdx.x;
  __shared__ float q[H_];
  for (int i = t; i < H_; i += 256) q[i] = query[(size_t)b * (4 * H_) + 3 * H_ + i];
  __syncthreads();
  for (int h = t; h < H_; h += 256) {
    const float* wr = Wa_w + (size_t)h * H_;
    float acc = 0.f;
    for (int k = 0; k < H_; k += 4) {
      f32x4 wv = *(const f32x4*)(wr + k);
      acc += wv.x * q[k] + wv.y * q[k + 1] + wv.z * q[k + 2] + wv.w * q[k + 3];
    }
    wqb[b * H_ + h] = acc + Wa_b[h] + Ua_b[h];
  }
}

// ---------------- kernel 3: fused GEMM (keys @ Ua^T) + tanh + Va-reduce ----------------
// 128x512 tile, 8 waves (2 row-halves x 4 col-quarters), single-barrier dbuf pipeline.
__global__ __launch_bounds__(512, 2) void k_gemm_score(
    const float* __restrict__ keys, const short* __restrict__ uab_t,
    const float* __restrict__ wqb, const float* __restrict__ va,
    float* __restrict__ scores_p) {
  __shared__ short As[2][BM * BK];   // 2 x 8 KB
  __shared__ short Bs[2][BN * BK];   // 2 x 32 KB

  // XCD-grouped swizzle: both nt blocks of an mt land on one XCD, adjacent slots.
  const int bid = blockIdx.x;
  const int mt = ((bid & 7) << 6) + (bid >> 4);   // 0..511
  const int nt = (bid >> 3) & 1;                  // 0..1
  const int r0 = mt * BM;
  const int h0 = nt * BN;

  const int t = threadIdx.x;
  const int lane = t & 63;
  const int w = t >> 6;        // 0..7
  const int wm = w >> 2;       // 0..1 row half (64 rows)
  const int wn = w & 3;        // 0..3 col quarter (128 cols)

  f32x4 acc[4][8] = {};

  // ---- A staging: thread t -> row t>>2, k-quarter t&3; swizzled ds_write slot ----
  const int ar = t >> 2;
  const int aq = t & 3;
  const float* aptr = keys + (size_t)(r0 + ar) * D2_ + aq * 8;
  const int awoff = ar * BK + ((aq ^ (ar & 3)) << 3);   // shorts

  // ---- B staging: global_load_lds, 4 chunks of 1 KB per wave ----
  const short* bsrc = uab_t + (size_t)nt * NKS * (BN * BK) + (w * 4) * 512 + lane * 8;
  const int bdoff = (w * 4) * 512;                      // shorts, wave-uniform

  // ---- fragment LDS offsets (constant per thread; shorts) ----
  int aoff[4], boff[8];
  {
    const int lrow = lane & 15;
    const int q = lane >> 4;
    #pragma unroll
    for (int m = 0; m < 4; ++m) {
      int row = wm * 64 + m * 16 + lrow;
      aoff[m] = row * BK + ((q ^ (row & 3)) << 3);
    }
    #pragma unroll
    for (int n = 0; n < 8; ++n) {
      int col = wn * 128 + n * 16 + lrow;
      boff[n] = col * BK + ((q ^ (col & 3)) << 3);
    }
  }

  // ---- prologue: stage step 0, prefetch A(1) ----
  f32x4 va0 = *(const f32x4*)(aptr);
  f32x4 va1 = *(const f32x4*)(aptr + 4);
  aptr += BK;
  *(short8*)&As[0][awoff] = cvt8(va0, va1);
  #pragma unroll
  for (int i = 0; i < 4; ++i) gload16(bsrc + i * 512, &Bs[0][bdoff + i * 512]);
  bsrc += BN * BK;
  va0 = *(const f32x4*)(aptr);
  va1 = *(const f32x4*)(aptr + 4);
  aptr += BK;

  int cur = 0;
  #pragma unroll 1
  for (int ks = 0; ks < NKS; ++ks) {
    __syncthreads();   // drains: B(ks) gload, As(ks) write, A(ks+1) reg loads
    if (ks < NKS - 1) {
      // stage ks+1 into alternate buffers; prefetch A(ks+2) into regs
      #pragma unroll
      for (int i = 0; i < 4; ++i) gload16(bsrc + i * 512, &Bs[cur ^ 1][bdoff + i * 512]);
      bsrc += BN * BK;
      *(short8*)&As[cur ^ 1][awoff] = cvt8(va0, va1);
      if (ks < NKS - 2) {
        va0 = *(const f32x4*)(aptr);
        va1 = *(const f32x4*)(aptr + 4);
        aptr += BK;
      }
    }
    // compute on cur
    const short* Ab = As[cur];
    const short* Bb = Bs[cur];
    short8 af[4], bfr[8];
    #pragma unroll
    for (int m = 0; m < 4; ++m) af[m] = *(const short8*)&Ab[aoff[m]];
    #pragma unroll
    for (int n = 0; n < 8; ++n) bfr[n] = *(const short8*)&Bb[boff[n]];
    #pragma unroll
    for (int m = 0; m < 4; ++m)
      #pragma unroll
      for (int n = 0; n < 8; ++n)
        acc[m][n] = __builtin_amdgcn_mfma_f32_16x16x32_bf16(af[m], bfr[n], acc[m][n], 0, 0, 0);
    cur ^= 1;
  }

  // ---- epilogue: tanh + Va-weighted row-reduce ----
  // C/D layout: col = lane&15, row = (lane>>4)*4 + reg
  const int lgrp = lane >> 4;
  const int lc = lane & 15;
  float vah[8];
  #pragma unroll
  for (int n = 0; n < 8; ++n) vah[n] = va[h0 + wn * 128 + n * 16 + lc];
  #pragma unroll
  for (int m = 0; m < 4; ++m) {
    #pragma unroll
    for (int reg = 0; reg < 4; ++reg) {
      int row = wm * 64 + m * 16 + lgrp * 4 + reg;
      int r = r0 + row;
      int bb = r & (B_ - 1);
      const float* wrow = wqb + bb * H_ + h0 + wn * 128 + lc;
      float s = 0.f;
      #pragma unroll
      for (int n = 0; n < 8; ++n)
        s += vah[n] * fast_tanh(acc[m][n][reg] + wrow[n * 16]);
      s += __shfl_xor(s, 1);
      s += __shfl_xor(s, 2);
      s += __shfl_xor(s, 4);
      s += __shfl_xor(s, 8);
      if (lc == 0) scores_p[(size_t)r * 8 + nt * 4 + wn] = s;
    }
  }
}

// ---------------- kernel 4: reduce partials + softmax -> weights ----------------
__global__ void k_softmax(const float* __restrict__ scores_p, float* __restrict__ out) {
  int b = blockIdx.x;
  int t = threadIdx.x;
  __shared__ float sc[S_];
  __shared__ float red[4];
  float lmax = -3.4e38f;
  #pragma unroll
  for (int i = 0; i < 8; ++i) {
    int s = t + i * 256;
    const float* p = scores_p + ((size_t)s * B_ + b) * 8;   // one 32B chunk
    f32x4 p0 = *(const f32x4*)p;
    f32x4 p1 = *(const f32x4*)(p + 4);
    float v = p0.x + p0.y + p0.z + p0.w + p1.x + p1.y + p1.z + p1.w;
    sc[s] = v;
    lmax = fmaxf(lmax, v);
  }
  #pragma unroll
  for (int o = 32; o >= 1; o >>= 1) lmax = fmaxf(lmax, __shfl_xor(lmax, o));
  if ((t & 63) == 0) red[t >> 6] = lmax;
  __syncthreads();
  float gmax = fmaxf(fmaxf(red[0], red[1]), fmaxf(red[2], red[3]));
  __syncthreads();
  float lsum = 0.f;
  #pragma unroll
  for (int i = 0; i < 8; ++i) {
    int s = t + i * 256;
    float e = __builtin_amdgcn_exp2f((sc[s] - gmax) * 1.4426950408889634f);
    sc[s] = e;
    lsum += e;
  }
  #pragma unroll
  for (int o = 32; o >= 1; o >>= 1) lsum += __shfl_xor(lsum, o);
  if ((t & 63) == 0) red[t >> 6] = lsum;
  __syncthreads();
  float inv = 1.0f / (red[0] + red[1] + red[2] + red[3]);
  for (int i = 0; i < 8; ++i) {
    int s = t + i * 256;
    out[(size_t)65536 + b * S_ + s] = sc[s] * inv;
  }
}

// ---------------- kernel 5: context partials ----------------
__global__ void k_ctx_partial(const float* __restrict__ keys, const float* __restrict__ wts,
                              float* __restrict__ cp) {
  int b = blockIdx.x;    // 32
  int dc = blockIdx.y;   // 2
  int scn = blockIdx.z;  // 8
  int t = threadIdx.x;
  __shared__ float wl[256];
  int s0 = scn * 256;
  wl[t] = wts[b * S_ + s0 + t];
  __syncthreads();
  int d = dc * 1024 + t * 4;
  f32x4 acc = {};
  #pragma unroll 4
  for (int i = 0; i < 256; ++i) {
    int s = s0 + i;
    f32x4 kv = *(const f32x4*)(keys + ((size_t)s * B_ + b) * D2_ + d);
    acc += kv * wl[i];
  }
  *(f32x4*)(cp + ((size_t)scn * B_ + b) * D2_ + d) = acc;
}

// ---------------- kernel 6: reduce context partials ----------------
__global__ void k_ctx_reduce(const float* __restrict__ cp, float* __restrict__ out) {
  int i = blockIdx.x * 256 + threadIdx.x;
  float s = 0.f;
  #pragma unroll
  for (int j = 0; j < 8; ++j) s += cp[(size_t)j * 65536 + i];
  out[i] = s;
}

extern "C" void kernel_launch(void* const* d_in, const int* in_sizes, int n_in,
                              void* d_out, int out_size, void* d_ws, size_t ws_size,
                              hipStream_t stream) {
  const float* query = (const float*)d_in[0];
  const float* keys  = (const float*)d_in[1];
  const float* Wa_w  = (const float*)d_in[2];
  const float* Wa_b  = (const float*)d_in[3];
  const float* Ua_w  = (const float*)d_in[4];
  const float* Ua_b  = (const float*)d_in[5];
  const float* Va_w  = (const float*)d_in[6];
  // Va_b (d_in[7]) intentionally unused: softmax is shift-invariant.
  float* out = (float*)d_out;

  char* ws = (char*)d_ws;
  short* uab_t = (short*)(ws);                                  // 4 MB tiled+swizzled bf16 Ua_w
  float* wqb = (float*)(ws + 4u * 1024 * 1024);                 // 128 KB
  float* sp  = (float*)(ws + 4u * 1024 * 1024 + 128 * 1024);    // 2 MB score partials
  float* cp  = (float*)(ws + 6u * 1024 * 1024 + 256 * 1024);    // 2 MB ctx partials

  hipLaunchKernelGGL(k_convert_ua, dim3(1024), dim3(256), 0, stream, Ua_w, uab_t);
  hipLaunchKernelGGL(k_wq, dim3(32), dim3(256), 0, stream, query, Wa_w, Wa_b, Ua_b, wqb);
  hipLaunchKernelGGL(k_gemm_score, dim3(1024), dim3(512), 0, stream, keys, uab_t, wqb, Va_w, sp);
  hipLaunchKernelGGL(k_softmax, dim3(32), dim3(256), 0, stream, sp, out);
  hipLaunchKernelGGL(k_ctx_partial, dim3(32, 2, 8), dim3(256), 0, stream, keys, out + 65536, cp);
  hipLaunchKernelGGL(k_ctx_reduce, dim3(256), dim3(256), 0, stream, cp, out);
}

// Round 3
// 659.991 us; speedup vs baseline: 1.2728x; 1.0600x over previous
//
#include <hip/hip_runtime.h>
#include <hip/hip_bf16.h>

typedef __attribute__((ext_vector_type(4))) float f32x4;
typedef __attribute__((ext_vector_type(8))) short short8;

#define B_   32
#define S_   2048
#define H_   1024
#define D2_  2048   // 2H
#define BM   256
#define BN   256
#define BK   64
#define NKT  32      // D2_/BK
#define TILE_SH 16384  // shorts per LDS tile (256*64)

// RNE f32 -> bf16
__device__ __forceinline__ short f2bf(float f) {
  unsigned u = __float_as_uint(f);
  u = (u + 0x7fffu + ((u >> 16) & 1u)) >> 16;
  return (short)u;
}

__device__ __forceinline__ short8 cvt8(f32x4 a, f32x4 b) {
  short8 o;
  o[0] = f2bf(a.x); o[1] = f2bf(a.y); o[2] = f2bf(a.z); o[3] = f2bf(a.w);
  o[4] = f2bf(b.x); o[5] = f2bf(b.y); o[6] = f2bf(b.z); o[7] = f2bf(b.w);
  return o;
}

// tanh via hardware exp2: tanh(x) = 1 - 2/(2^(2x*log2e)+1). Correct limits at +-inf.
__device__ __forceinline__ float fast_tanh(float x) {
  float e = __builtin_amdgcn_exp2f(x * 2.885390081777927f);
  return 1.0f - 2.0f * __builtin_amdgcn_rcpf(e + 1.0f);
}

__device__ __forceinline__ void gload16(const short* g, short* l) {
  __builtin_amdgcn_global_load_lds((const __attribute__((address_space(1))) void*)g,
                                   (__attribute__((address_space(3))) void*)l, 16, 0, 0);
}

// ---------------- kernel 1: Ua_w f32 -> bf16 as the exact LDS tile image ----------------
// Layout: [nt(4)][kt(32)] tiles of 32KB; within tile: row-major rows 0..255 (h within
// nt-tile), each row = 8 slots x 16B; slot s' holds source k-quarter q = s' ^ (row&7).
__global__ void k_convert_ua(const float* __restrict__ src, short* __restrict__ dst) {
  int idx = blockIdx.x * 256 + threadIdx.x;    // 262144 x 16B
  int wu  = idx & 2047;                        // 16B unit within tile
  int kt  = (idx >> 11) & 31;
  int nt  = idx >> 16;
  int row = wu >> 3;
  int sl  = wu & 7;
  int q   = sl ^ (row & 7);
  const float* s = src + (size_t)(nt * 256 + row) * D2_ + kt * 64 + q * 8;
  f32x4 a = *(const f32x4*)s;
  f32x4 b = *(const f32x4*)(s + 4);
  *(short8*)(dst + (size_t)idx * 8) = cvt8(a, b);
}

// ---------------- kernel 2: wqb[b][h] = q[b] . Wa_w[h] + Wa_b[h] + Ua_b[h] ----------------
__global__ void k_wq(const float* __restrict__ query, const float* __restrict__ Wa_w,
                     const float* __restrict__ Wa_b, const float* __restrict__ Ua_b,
                     float* __restrict__ wqb) {
  int b = blockIdx.x;       // 32
  int hc = blockIdx.y;      // 8
  int t = threadIdx.x;      // 256
  __shared__ float q[H_];
  for (int i = t; i < H_; i += 256) q[i] = query[(size_t)b * (4 * H_) + 3 * H_ + i];
  __syncthreads();
  int h = hc * 128 + (t >> 1);
  int kh = (t & 1) * 512;
  const float* wr = Wa_w + (size_t)h * H_ + kh;
  float acc = 0.f;
  #pragma unroll 8
  for (int k = 0; k < 512; k += 4) {
    f32x4 wv = *(const f32x4*)(wr + k);
    acc += wv.x * q[kh + k] + wv.y * q[kh + k + 1] + wv.z * q[kh + k + 2] + wv.w * q[kh + k + 3];
  }
  acc += __shfl_xor(acc, 1);
  if ((t & 1) == 0) wqb[b * H_ + h] = acc + Wa_b[h] + Ua_b[h];
}

// ---------------- kernel 3: fused GEMM (keys @ Ua^T) + tanh + Va-reduce ----------------
// 256x256 tile, BK=64, 8 waves (2x4), 4-phase pipelined K-loop with counted waits.
#define AF_READ(mA, mB)                                         \
  af[0] = *(const short8*)&Ac[aread0 + (mA) * 1024];            \
  af[1] = *(const short8*)&Ac[aread1 + (mA) * 1024];            \
  af[2] = *(const short8*)&Ac[aread0 + (mB) * 1024];            \
  af[3] = *(const short8*)&Ac[aread1 + (mB) * 1024];

#define MFMA_CLUSTER(mA, mB)                                                                      \
  __builtin_amdgcn_sched_barrier(0);                                                              \
  __builtin_amdgcn_s_setprio(1);                                                                  \
  _Pragma("unroll")                                                                               \
  for (int n = 0; n < 4; ++n) {                                                                   \
    acc[mA][n] = __builtin_amdgcn_mfma_f32_16x16x32_bf16(af[0], bf[2*n],   acc[mA][n], 0, 0, 0);  \
    acc[mA][n] = __builtin_amdgcn_mfma_f32_16x16x32_bf16(af[1], bf[2*n+1], acc[mA][n], 0, 0, 0);  \
    acc[mB][n] = __builtin_amdgcn_mfma_f32_16x16x32_bf16(af[2], bf[2*n],   acc[mB][n], 0, 0, 0);  \
    acc[mB][n] = __builtin_amdgcn_mfma_f32_16x16x32_bf16(af[3], bf[2*n+1], acc[mB][n], 0, 0, 0);  \
  }                                                                                               \
  __builtin_amdgcn_s_setprio(0);                                                                  \
  __builtin_amdgcn_sched_barrier(0);

__global__ __launch_bounds__(512, 2) void k_gemm_score(
    const float* __restrict__ keys, const short* __restrict__ uab_t,
    const float* __restrict__ wqb, const float* __restrict__ va,
    float* __restrict__ scores_p) {
  __shared__ short As[2][TILE_SH];   // 2 x 32 KB
  __shared__ short Bs[2][TILE_SH];   // 2 x 32 KB

  // bijective XCD swizzle: the 4 nt-blocks of an mt are adjacent on one XCD
  const int bid = blockIdx.x;
  const int g = (bid & 7) * 128 + (bid >> 3);
  const int mt = g >> 2;               // 0..255
  const int nt = g & 3;                // 0..3
  const int r0 = mt * BM;
  const int h0 = nt * BN;

  const int t = threadIdx.x;
  const int lane = t & 63;
  const int w = t >> 6;
  const int wm = w >> 2;               // 0..1 (128-row half)
  const int wn = w & 3;                // 0..3 (64-col quarter)

  f32x4 acc[8][4] = {};

  // ---- A staging map: thread -> row t>>1, k-half t&1 (32 f32) ----
  const int arow = t >> 1;
  const int ahalf = t & 1;
  const float* abase = keys + (size_t)(r0 + arow) * D2_ + ahalf * 32;
  int awoff[4];
  #pragma unroll
  for (int j = 0; j < 4; ++j)
    awoff[j] = arow * 64 + ((((ahalf << 2) | j) ^ (arow & 7)) << 3);

  // ---- B staging: gload16 batches of 8KB; LDS dest wave-uniform, source per-lane ----
  const short* bbase = uab_t + (size_t)nt * NKT * TILE_SH + t * 8;
  const int bwu = w * 512;             // wave-uniform shorts within a batch

  // ---- fragment read offsets (shorts); row&7 == lr&7 everywhere ----
  const int lr = lane & 15;
  const int lq = lane >> 4;
  const int s0 = lq ^ (lr & 7);
  const int s1 = s0 ^ 4;
  const int aread0 = (wm * 128 + lr) * 64 + s0 * 8;   // ksub=0
  const int aread1 = (wm * 128 + lr) * 64 + s1 * 8;   // ksub=1
  const int bread0 = (wn * 64 + lr) * 64 + s0 * 8;
  const int bread1 = (wn * 64 + lr) * 64 + s1 * 8;

  // ---- prologue: stage tile 0 into buffer 0 ----
  {
    f32x4 v[8];
    #pragma unroll
    for (int j = 0; j < 8; ++j) v[j] = *(const f32x4*)(abase + j * 4);
    #pragma unroll
    for (int j = 0; j < 4; ++j)
      *(short8*)&As[0][awoff[j]] = cvt8(v[2 * j], v[2 * j + 1]);
    #pragma unroll
    for (int i = 0; i < 4; ++i)
      gload16(bbase + i * 4096, &Bs[0][i * 4096 + bwu]);
    asm volatile("s_waitcnt vmcnt(0) lgkmcnt(0)" ::: "memory");
    __builtin_amdgcn_s_barrier();
  }

  int cur = 0;
  f32x4 av[8];
  #pragma unroll 1
  for (int kt = 0; kt < NKT; ++kt) {
    const int nxt = cur ^ 1;
    const bool stage = (kt < NKT - 1);
    const float* anext = abase + (kt + 1) * BK;
    const short* bnext = bbase + (size_t)(kt + 1) * TILE_SH;
    const short* Ac = As[cur];
    const short* Bc = Bs[cur];
    short8 bf[8], af[4];

    // ---------- P0: all B frags + A frags m0,m1; issue next A f32 loads ----------
    #pragma unroll
    for (int n = 0; n < 4; ++n) {
      bf[2 * n]     = *(const short8*)&Bc[bread0 + n * 1024];
      bf[2 * n + 1] = *(const short8*)&Bc[bread1 + n * 1024];
    }
    AF_READ(0, 1)
    if (stage) {
      #pragma unroll
      for (int j = 0; j < 8; ++j) av[j] = *(const f32x4*)(anext + j * 4);
    }
    __builtin_amdgcn_s_barrier();
    MFMA_CLUSTER(0, 1)
    __builtin_amdgcn_s_barrier();

    // ---------- P1: A frags m2,m3; B gload batches 0,1 -> Bs[nxt] ----------
    AF_READ(2, 3)
    if (stage) {
      gload16(bnext + 0 * 4096, &Bs[nxt][0 * 4096 + bwu]);
      gload16(bnext + 1 * 4096, &Bs[nxt][1 * 4096 + bwu]);
    }
    __builtin_amdgcn_s_barrier();
    MFMA_CLUSTER(2, 3)
    __builtin_amdgcn_s_barrier();

    // ---------- P2: A frags m4,m5; B gload batches 2,3 ----------
    AF_READ(4, 5)
    if (stage) {
      gload16(bnext + 2 * 4096, &Bs[nxt][2 * 4096 + bwu]);
      gload16(bnext + 3 * 4096, &Bs[nxt][3 * 4096 + bwu]);
    }
    __builtin_amdgcn_s_barrier();
    MFMA_CLUSTER(4, 5)
    __builtin_amdgcn_s_barrier();

    // ---------- P3: A frags m6,m7; cvt+write next A; drain tile staging ----------
    AF_READ(6, 7)
    if (stage) {
      #pragma unroll
      for (int j = 0; j < 4; ++j)
        *(short8*)&As[nxt][awoff[j]] = cvt8(av[2 * j], av[2 * j + 1]);
    }
    asm volatile("s_waitcnt vmcnt(0) lgkmcnt(0)" ::: "memory");
    __builtin_amdgcn_s_barrier();
    MFMA_CLUSTER(6, 7)
    __builtin_amdgcn_s_barrier();

    cur ^= 1;
  }

  // ---- epilogue: tanh + Va-weighted row-reduce ----
  // C/D layout: col = lane&15, row = (lane>>4)*4 + reg
  const int lgrp = lane >> 4;
  const int lc = lane & 15;
  float vah[4];
  #pragma unroll
  for (int n = 0; n < 4; ++n) vah[n] = va[h0 + wn * 64 + n * 16 + lc];
  #pragma unroll
  for (int m = 0; m < 8; ++m) {
    #pragma unroll
    for (int reg = 0; reg < 4; ++reg) {
      int row = wm * 128 + m * 16 + lgrp * 4 + reg;
      int r = r0 + row;
      int bb = r & (B_ - 1);
      const float* wrow = wqb + bb * H_ + h0 + wn * 64 + lc;
      float s = 0.f;
      #pragma unroll
      for (int n = 0; n < 4; ++n)
        s += vah[n] * fast_tanh(acc[m][n][reg] + wrow[n * 16]);
      s += __shfl_xor(s, 1);
      s += __shfl_xor(s, 2);
      s += __shfl_xor(s, 4);
      s += __shfl_xor(s, 8);
      if (lc == 0) scores_p[(size_t)r * 16 + nt * 4 + wn] = s;
    }
  }
}

// ---------------- kernel 4: reduce 16 partials + softmax -> weights ----------------
__global__ void k_softmax(const float* __restrict__ scores_p, float* __restrict__ out) {
  int b = blockIdx.x;
  int t = threadIdx.x;
  __shared__ float sc[S_];
  __shared__ float red[4];
  float lmax = -3.4e38f;
  #pragma unroll
  for (int i = 0; i < 8; ++i) {
    int s = t + i * 256;
    const float* p = scores_p + ((size_t)s * B_ + b) * 16;   // one 64B line
    f32x4 p0 = *(const f32x4*)p;
    f32x4 p1 = *(const f32x4*)(p + 4);
    f32x4 p2 = *(const f32x4*)(p + 8);
    f32x4 p3 = *(const f32x4*)(p + 12);
    f32x4 ps = p0 + p1 + p2 + p3;
    float v = ps.x + ps.y + ps.z + ps.w;
    sc[s] = v;
    lmax = fmaxf(lmax, v);
  }
  #pragma unroll
  for (int o = 32; o >= 1; o >>= 1) lmax = fmaxf(lmax, __shfl_xor(lmax, o));
  if ((t & 63) == 0) red[t >> 6] = lmax;
  __syncthreads();
  float gmax = fmaxf(fmaxf(red[0], red[1]), fmaxf(red[2], red[3]));
  __syncthreads();
  float lsum = 0.f;
  #pragma unroll
  for (int i = 0; i < 8; ++i) {
    int s = t + i * 256;
    float e = __builtin_amdgcn_exp2f((sc[s] - gmax) * 1.4426950408889634f);
    sc[s] = e;
    lsum += e;
  }
  #pragma unroll
  for (int o = 32; o >= 1; o >>= 1) lsum += __shfl_xor(lsum, o);
  if ((t & 63) == 0) red[t >> 6] = lsum;
  __syncthreads();
  float inv = 1.0f / (red[0] + red[1] + red[2] + red[3]);
  for (int i = 0; i < 8; ++i) {
    int s = t + i * 256;
    out[(size_t)65536 + b * S_ + s] = sc[s] * inv;
  }
}

// ---------------- kernel 5: context partials ----------------
__global__ void k_ctx_partial(const float* __restrict__ keys, const float* __restrict__ wts,
                              float* __restrict__ cp) {
  int b = blockIdx.x;    // 32
  int dc = blockIdx.y;   // 2
  int scn = blockIdx.z;  // 8
  int t = threadIdx.x;
  __shared__ float wl[256];
  int s0 = scn * 256;
  wl[t] = wts[b * S_ + s0 + t];
  __syncthreads();
  int d = dc * 1024 + t * 4;
  f32x4 acc = {};
  #pragma unroll 4
  for (int i = 0; i < 256; ++i) {
    int s = s0 + i;
    f32x4 kv = *(const f32x4*)(keys + ((size_t)s * B_ + b) * D2_ + d);
    acc += kv * wl[i];
  }
  *(f32x4*)(cp + ((size_t)scn * B_ + b) * D2_ + d) = acc;
}

// ---------------- kernel 6: reduce context partials ----------------
__global__ void k_ctx_reduce(const float* __restrict__ cp, float* __restrict__ out) {
  int i = blockIdx.x * 256 + threadIdx.x;
  float s = 0.f;
  #pragma unroll
  for (int j = 0; j < 8; ++j) s += cp[(size_t)j * 65536 + i];
  out[i] = s;
}

extern "C" void kernel_launch(void* const* d_in, const int* in_sizes, int n_in,
                              void* d_out, int out_size, void* d_ws, size_t ws_size,
                              hipStream_t stream) {
  const float* query = (const float*)d_in[0];
  const float* keys  = (const float*)d_in[1];
  const float* Wa_w  = (const float*)d_in[2];
  const float* Wa_b  = (const float*)d_in[3];
  const float* Ua_w  = (const float*)d_in[4];
  const float* Ua_b  = (const float*)d_in[5];
  const float* Va_w  = (const float*)d_in[6];
  // Va_b (d_in[7]) intentionally unused: softmax is shift-invariant.
  float* out = (float*)d_out;

  char* ws = (char*)d_ws;
  short* uab_t = (short*)(ws);                                  // 4 MB tiled+swizzled bf16 Ua_w
  float* wqb = (float*)(ws + 4u * 1024 * 1024);                 // 128 KB
  float* sp  = (float*)(ws + 4u * 1024 * 1024 + 128 * 1024);    // 4 MB score partials (16/row)
  float* cp  = (float*)(ws + 8u * 1024 * 1024 + 256 * 1024);    // 2 MB ctx partials

  hipLaunchKernelGGL(k_convert_ua, dim3(1024), dim3(256), 0, stream, Ua_w, uab_t);
  hipLaunchKernelGGL(k_wq, dim3(32, 8), dim3(256), 0, stream, query, Wa_w, Wa_b, Ua_b, wqb);
  hipLaunchKernelGGL(k_gemm_score, dim3(1024), dim3(512), 0, stream, keys, uab_t, wqb, Va_w, sp);
  hipLaunchKernelGGL(k_softmax, dim3(32), dim3(256), 0, stream, sp, out);
  hipLaunchKernelGGL(k_ctx_partial, dim3(32, 2, 8), dim3(256), 0, stream, keys, out + 65536, cp);
  hipLaunchKernelGGL(k_ctx_reduce, dim3(256), dim3(256), 0, stream, cp, out);
}

// Round 5
// 544.448 us; speedup vs baseline: 1.5429x; 1.2122x over previous
//
#include <hip/hip_runtime.h>
#include <hip/hip_bf16.h>

typedef __attribute__((ext_vector_type(4))) float f32x4;
typedef __attribute__((ext_vector_type(8))) short short8;

#define B_   32
#define S_   2048
#define H_   1024
#define D2_  2048   // 2H
#define BM   256
#define BN   256
#define BK   64
#define NKT  32        // D2_/BK
#define TILE_SH 16384  // shorts per 256x64 LDS tile (32 KB)

// RNE f32 -> bf16
__device__ __forceinline__ short f2bf(float f) {
  unsigned u = __float_as_uint(f);
  u = (u + 0x7fffu + ((u >> 16) & 1u)) >> 16;
  return (short)u;
}

__device__ __forceinline__ short8 cvt8(f32x4 a, f32x4 b) {
  short8 o;
  o[0] = f2bf(a.x); o[1] = f2bf(a.y); o[2] = f2bf(a.z); o[3] = f2bf(a.w);
  o[4] = f2bf(b.x); o[5] = f2bf(b.y); o[6] = f2bf(b.z); o[7] = f2bf(b.w);
  return o;
}

// tanh via hardware exp2: tanh(x) = 1 - 2/(2^(2x*log2e)+1). Correct limits at +-inf.
__device__ __forceinline__ float fast_tanh(float x) {
  float e = __builtin_amdgcn_exp2f(x * 2.885390081777927f);
  return 1.0f - 2.0f * __builtin_amdgcn_rcpf(e + 1.0f);
}

__device__ __forceinline__ void gload16(const short* g, short* l) {
  __builtin_amdgcn_global_load_lds((const __attribute__((address_space(1))) void*)g,
                                   (__attribute__((address_space(3))) void*)l, 16, 0, 0);
}

// ---------------- kernel 1a: Ua_w f32 -> bf16 tile image ----------------
// [nt(4)][kt(32)] tiles of 32KB; in-tile: 256 rows x 8 slots x 16B, slot s' holds
// source k-quarter q = s' ^ (row&7).
__global__ void k_convert_ua(const float* __restrict__ src, short* __restrict__ dst) {
  int idx = blockIdx.x * 256 + threadIdx.x;    // 262144 x 16B units
  int wu  = idx & 2047;
  int kt  = (idx >> 11) & 31;
  int nt  = idx >> 16;
  int row = wu >> 3;
  int sl  = wu & 7;
  int q   = sl ^ (row & 7);
  const float* s = src + (size_t)(nt * 256 + row) * D2_ + kt * 64 + q * 8;
  f32x4 a = *(const f32x4*)s;
  f32x4 b = *(const f32x4*)(s + 4);
  *(short8*)(dst + (size_t)idx * 8) = cvt8(a, b);
}

// ---------------- kernel 1b: keys f32 -> bf16 tile image ----------------
// [mt(256)][kt(32)] tiles, same in-tile layout (row = GEMM row r within mt).
// 2^24 16B units total -> grid 65536 x 256.
__global__ void k_convert_keys(const float* __restrict__ src, short* __restrict__ dst) {
  int idx = blockIdx.x * 256 + threadIdx.x;    // 16777216 x 16B units
  int wu  = idx & 2047;
  int kt  = (idx >> 11) & 31;
  int mt  = idx >> 16;                         // 0..255
  int row = wu >> 3;
  int sl  = wu & 7;
  int q   = sl ^ (row & 7);
  const float* s = src + (size_t)(mt * 256 + row) * D2_ + kt * 64 + q * 8;
  f32x4 a = *(const f32x4*)s;
  f32x4 b = *(const f32x4*)(s + 4);
  *(short8*)(dst + (size_t)idx * 8) = cvt8(a, b);
}

// ---------------- kernel 2: wqb[b][h] = q[b] . Wa_w[h] + Wa_b[h] + Ua_b[h] ----------------
__global__ void k_wq(const float* __restrict__ query, const float* __restrict__ Wa_w,
                     const float* __restrict__ Wa_b, const float* __restrict__ Ua_b,
                     float* __restrict__ wqb) {
  int b = blockIdx.x;       // 32
  int hc = blockIdx.y;      // 8
  int t = threadIdx.x;      // 256
  __shared__ float q[H_];
  for (int i = t; i < H_; i += 256) q[i] = query[(size_t)b * (4 * H_) + 3 * H_ + i];
  __syncthreads();
  int h = hc * 128 + (t >> 1);
  int kh = (t & 1) * 512;
  const float* wr = Wa_w + (size_t)h * H_ + kh;
  float acc = 0.f;
  #pragma unroll 8
  for (int k = 0; k < 512; k += 4) {
    f32x4 wv = *(const f32x4*)(wr + k);
    acc += wv.x * q[kh + k] + wv.y * q[kh + k + 1] + wv.z * q[kh + k + 2] + wv.w * q[kh + k + 3];
  }
  acc += __shfl_xor(acc, 1);
  if ((t & 1) == 0) wqb[b * H_ + h] = acc + Wa_b[h] + Ua_b[h];
}

// ---------------- kernel 3: fused GEMM (keys @ Ua^T) + tanh + Va-reduce ----------------
#define AF_READ(mA, mB)                                         \
  af[0] = *(const short8*)&Ac[aread0 + (mA) * 1024];            \
  af[1] = *(const short8*)&Ac[aread1 + (mA) * 1024];            \
  af[2] = *(const short8*)&Ac[aread0 + (mB) * 1024];            \
  af[3] = *(const short8*)&Ac[aread1 + (mB) * 1024];

#define MFMA16(mA, mB)                                                                            \
  __builtin_amdgcn_s_setprio(1);                                                                  \
  _Pragma("unroll")                                                                               \
  for (int n = 0; n < 4; ++n) {                                                                   \
    acc[mA][n] = __builtin_amdgcn_mfma_f32_16x16x32_bf16(af[0], bf[2*n],   acc[mA][n], 0, 0, 0);  \
    acc[mA][n] = __builtin_amdgcn_mfma_f32_16x16x32_bf16(af[1], bf[2*n+1], acc[mA][n], 0, 0, 0);  \
    acc[mB][n] = __builtin_amdgcn_mfma_f32_16x16x32_bf16(af[2], bf[2*n],   acc[mB][n], 0, 0, 0);  \
    acc[mB][n] = __builtin_amdgcn_mfma_f32_16x16x32_bf16(af[3], bf[2*n+1], acc[mB][n], 0, 0, 0);  \
  }                                                                                               \
  __builtin_amdgcn_s_setprio(0);

#define STAGE4(src_, dst_)                         \
  gload16((src_) + 0 * 4096, (dst_) + 0 * 4096 + wu); \
  gload16((src_) + 1 * 4096, (dst_) + 1 * 4096 + wu); \
  gload16((src_) + 2 * 4096, (dst_) + 2 * 4096 + wu); \
  gload16((src_) + 3 * 4096, (dst_) + 3 * 4096 + wu);

__global__ __launch_bounds__(512, 2) void k_gemm_score(
    const short* __restrict__ keys_bf, const short* __restrict__ uab_t,
    const float* __restrict__ wqb, const float* __restrict__ va,
    float* __restrict__ scores_p) {
  __shared__ short As[2][TILE_SH];   // 2 x 32 KB
  __shared__ short Bs[2][TILE_SH];   // 2 x 32 KB

  // bijective XCD swizzle: the 4 nt-blocks of an mt adjacent on one XCD
  const int bid = blockIdx.x;
  const int g = (bid & 7) * 128 + (bid >> 3);
  const int mt = g >> 2;               // 0..255
  const int nt = g & 3;                // 0..3
  const int r0 = mt * BM;
  const int h0 = nt * BN;

  const int t = threadIdx.x;
  const int lane = t & 63;
  const int w = t >> 6;
  const int wm = w >> 2;               // 0..1 (128-row half)
  const int wn = w & 3;                // 0..3 (64-col quarter)

  f32x4 acc[8][4] = {};

  // staging sources: unit u = t + 512*i of each 2048-unit tile; LDS dest linear
  const short* abase = keys_bf + (size_t)mt * (NKT * TILE_SH) + t * 8;
  const short* bbase = uab_t  + (size_t)nt * (NKT * TILE_SH) + t * 8;
  const int wu = w * 512;              // wave-uniform shorts within a 4096-short batch

  // fragment read offsets (shorts); row&7 == (lane&15)&7 for 16-row frags
  const int lr = lane & 15;
  const int lq = lane >> 4;
  const int sl0 = lq ^ (lr & 7);
  const int aread0 = (wm * 128 + lr) * 64 + sl0 * 8;
  const int aread1 = aread0 ^ 32;      // slot ^4  (ksub=1)
  const int bread0 = (wn * 64 + lr) * 64 + sl0 * 8;
  const int bread1 = bread0 ^ 32;

  // ---- prologue: stage tile 0 ----
  {
    STAGE4(abase, &As[0][0])
    STAGE4(bbase, &Bs[0][0])
    asm volatile("s_waitcnt vmcnt(0)" ::: "memory");
    __builtin_amdgcn_s_barrier();
  }

  #pragma unroll 1
  for (int kt = 0; kt < NKT; ++kt) {
    const int cb = kt & 1;
    const bool stage = (kt < NKT - 1);
    const short* Ac = As[cb];
    const short* Bc = Bs[cb];
    const short* anext = abase + (size_t)(kt + 1) * TILE_SH;
    const short* bnext = bbase + (size_t)(kt + 1) * TILE_SH;
    short* Anb = &As[cb ^ 1][0];
    short* Bnb = &Bs[cb ^ 1][0];
    short8 bf[8], af[4];

    // ---------- P0: all B frags + A frags m0,m1; issue next A stage ----------
    #pragma unroll
    for (int n = 0; n < 4; ++n) {
      bf[2 * n]     = *(const short8*)&Bc[bread0 + n * 1024];
      bf[2 * n + 1] = *(const short8*)&Bc[bread1 + n * 1024];
    }
    AF_READ(0, 1)
    if (stage) { STAGE4(anext, Anb) }
    __builtin_amdgcn_s_barrier();
    asm volatile("s_waitcnt lgkmcnt(0)" ::: "memory");
    MFMA16(0, 1)
    __builtin_amdgcn_s_barrier();

    // ---------- P1: A frags m2,m3; issue next B stage ----------
    AF_READ(2, 3)
    if (stage) { STAGE4(bnext, Bnb) }
    __builtin_amdgcn_s_barrier();
    asm volatile("s_waitcnt lgkmcnt(0)" ::: "memory");
    MFMA16(2, 3)
    __builtin_amdgcn_s_barrier();

    // ---------- P2: A frags m4,m5 ----------
    AF_READ(4, 5)
    __builtin_amdgcn_s_barrier();
    asm volatile("s_waitcnt lgkmcnt(0)" ::: "memory");
    MFMA16(4, 5)
    __builtin_amdgcn_s_barrier();

    // ---------- P3: A frags m6,m7; drain staging before buffer flip ----------
    AF_READ(6, 7)
    __builtin_amdgcn_s_barrier();
    asm volatile("s_waitcnt lgkmcnt(0)" ::: "memory");
    MFMA16(6, 7)
    asm volatile("s_waitcnt vmcnt(0)" ::: "memory");
    __builtin_amdgcn_s_barrier();
  }

  // ---- epilogue: tanh + Va-weighted row-reduce ----
  // C/D layout: col = lane&15, row = (lane>>4)*4 + reg
  const int lgrp = lane >> 4;
  const int lc = lane & 15;
  float vah[4];
  #pragma unroll
  for (int n = 0; n < 4; ++n) vah[n] = va[h0 + wn * 64 + n * 16 + lc];
  #pragma unroll
  for (int m = 0; m < 8; ++m) {
    #pragma unroll
    for (int reg = 0; reg < 4; ++reg) {
      int row = wm * 128 + m * 16 + lgrp * 4 + reg;
      int r = r0 + row;
      int bb = r & (B_ - 1);
      const float* wrow = wqb + bb * H_ + h0 + wn * 64 + lc;
      float s = 0.f;
      #pragma unroll
      for (int n = 0; n < 4; ++n)
        s += vah[n] * fast_tanh(acc[m][n][reg] + wrow[n * 16]);
      s += __shfl_xor(s, 1);
      s += __shfl_xor(s, 2);
      s += __shfl_xor(s, 4);
      s += __shfl_xor(s, 8);
      if (lc == 0) scores_p[(size_t)r * 16 + nt * 4 + wn] = s;
    }
  }
}

// ---------------- fallback GEMM (reg-staged A; used when ws too small) ----------------
__global__ __launch_bounds__(512, 2) void k_gemm_rs(
    const float* __restrict__ keys, const short* __restrict__ uab_t,
    const float* __restrict__ wqb, const float* __restrict__ va,
    float* __restrict__ scores_p) {
  __shared__ short As[2][TILE_SH];
  __shared__ short Bs[2][TILE_SH];
  const int bid = blockIdx.x;
  const int g = (bid & 7) * 128 + (bid >> 3);
  const int mt = g >> 2;
  const int nt = g & 3;
  const int r0 = mt * BM;
  const int h0 = nt * BN;
  const int t = threadIdx.x;
  const int lane = t & 63;
  const int w = t >> 6;
  const int wm = w >> 2;
  const int wn = w & 3;
  f32x4 acc[8][4] = {};
  const int arow = t >> 1;
  const int ahalf = t & 1;
  const float* abase = keys + (size_t)(r0 + arow) * D2_ + ahalf * 32;
  int awoff[4];
  #pragma unroll
  for (int j = 0; j < 4; ++j)
    awoff[j] = arow * 64 + ((((ahalf << 2) | j) ^ (arow & 7)) << 3);
  const short* bbase = uab_t + (size_t)nt * NKT * TILE_SH + t * 8;
  const int wu = w * 512;
  const int lr = lane & 15;
  const int lq = lane >> 4;
  const int sl0 = lq ^ (lr & 7);
  const int aread0 = (wm * 128 + lr) * 64 + sl0 * 8;
  const int aread1 = aread0 ^ 32;
  const int bread0 = (wn * 64 + lr) * 64 + sl0 * 8;
  const int bread1 = bread0 ^ 32;
  {
    f32x4 v[8];
    #pragma unroll
    for (int j = 0; j < 8; ++j) v[j] = *(const f32x4*)(abase + j * 4);
    #pragma unroll
    for (int j = 0; j < 4; ++j)
      *(short8*)&As[0][awoff[j]] = cvt8(v[2 * j], v[2 * j + 1]);
    STAGE4(bbase, &Bs[0][0])
    asm volatile("s_waitcnt vmcnt(0) lgkmcnt(0)" ::: "memory");
    __builtin_amdgcn_s_barrier();
  }
  f32x4 av[8];
  #pragma unroll 1
  for (int kt = 0; kt < NKT; ++kt) {
    const int cb = kt & 1;
    const bool stage = (kt < NKT - 1);
    const float* anext = abase + (kt + 1) * BK;
    const short* bnext = bbase + (size_t)(kt + 1) * TILE_SH;
    short* Bnb = &Bs[cb ^ 1][0];
    const short* Ac = As[cb];
    const short* Bc = Bs[cb];
    short8 bf[8], af[4];
    #pragma unroll
    for (int n = 0; n < 4; ++n) {
      bf[2 * n]     = *(const short8*)&Bc[bread0 + n * 1024];
      bf[2 * n + 1] = *(const short8*)&Bc[bread1 + n * 1024];
    }
    AF_READ(0, 1)
    if (stage) {
      #pragma unroll
      for (int j = 0; j < 8; ++j) av[j] = *(const f32x4*)(anext + j * 4);
    }
    __builtin_amdgcn_s_barrier();
    asm volatile("s_waitcnt lgkmcnt(0)" ::: "memory");
    MFMA16(0, 1)
    __builtin_amdgcn_s_barrier();
    AF_READ(2, 3)
    if (stage) {
      gload16(bnext + 0 * 4096, Bnb + 0 * 4096 + wu);
      gload16(bnext + 1 * 4096, Bnb + 1 * 4096 + wu);
    }
    __builtin_amdgcn_s_barrier();
    asm volatile("s_waitcnt lgkmcnt(0)" ::: "memory");
    MFMA16(2, 3)
    __builtin_amdgcn_s_barrier();
    AF_READ(4, 5)
    if (stage) {
      gload16(bnext + 2 * 4096, Bnb + 2 * 4096 + wu);
      gload16(bnext + 3 * 4096, Bnb + 3 * 4096 + wu);
    }
    __builtin_amdgcn_s_barrier();
    asm volatile("s_waitcnt lgkmcnt(0)" ::: "memory");
    MFMA16(4, 5)
    __builtin_amdgcn_s_barrier();
    AF_READ(6, 7)
    if (stage) {
      #pragma unroll
      for (int j = 0; j < 4; ++j)
        *(short8*)&As[cb ^ 1][awoff[j]] = cvt8(av[2 * j], av[2 * j + 1]);
    }
    __builtin_amdgcn_s_barrier();
    asm volatile("s_waitcnt lgkmcnt(0)" ::: "memory");
    MFMA16(6, 7)
    asm volatile("s_waitcnt vmcnt(0) lgkmcnt(0)" ::: "memory");
    __builtin_amdgcn_s_barrier();
  }
  const int lgrp = lane >> 4;
  const int lc = lane & 15;
  float vah[4];
  #pragma unroll
  for (int n = 0; n < 4; ++n) vah[n] = va[h0 + wn * 64 + n * 16 + lc];
  #pragma unroll
  for (int m = 0; m < 8; ++m) {
    #pragma unroll
    for (int reg = 0; reg < 4; ++reg) {
      int row = wm * 128 + m * 16 + lgrp * 4 + reg;
      int r = r0 + row;
      int bb = r & (B_ - 1);
      const float* wrow = wqb + bb * H_ + h0 + wn * 64 + lc;
      float s = 0.f;
      #pragma unroll
      for (int n = 0; n < 4; ++n)
        s += vah[n] * fast_tanh(acc[m][n][reg] + wrow[n * 16]);
      s += __shfl_xor(s, 1);
      s += __shfl_xor(s, 2);
      s += __shfl_xor(s, 4);
      s += __shfl_xor(s, 8);
      if (lc == 0) scores_p[(size_t)r * 16 + nt * 4 + wn] = s;
    }
  }
}

// ---------------- kernel 4: reduce 16 partials + softmax -> weights ----------------
__global__ void k_softmax(const float* __restrict__ scores_p, float* __restrict__ out) {
  int b = blockIdx.x;
  int t = threadIdx.x;
  __shared__ float sc[S_];
  __shared__ float red[4];
  float lmax = -3.4e38f;
  #pragma unroll
  for (int i = 0; i < 8; ++i) {
    int s = t + i * 256;
    const float* p = scores_p + ((size_t)s * B_ + b) * 16;
    f32x4 p0 = *(const f32x4*)p;
    f32x4 p1 = *(const f32x4*)(p + 4);
    f32x4 p2 = *(const f32x4*)(p + 8);
    f32x4 p3 = *(const f32x4*)(p + 12);
    f32x4 ps = p0 + p1 + p2 + p3;
    float v = ps.x + ps.y + ps.z + ps.w;
    sc[s] = v;
    lmax = fmaxf(lmax, v);
  }
  #pragma unroll
  for (int o = 32; o >= 1; o >>= 1) lmax = fmaxf(lmax, __shfl_xor(lmax, o));
  if ((t & 63) == 0) red[t >> 6] = lmax;
  __syncthreads();
  float gmax = fmaxf(fmaxf(red[0], red[1]), fmaxf(red[2], red[3]));
  __syncthreads();
  float lsum = 0.f;
  #pragma unroll
  for (int i = 0; i < 8; ++i) {
    int s = t + i * 256;
    float e = __builtin_amdgcn_exp2f((sc[s] - gmax) * 1.4426950408889634f);
    sc[s] = e;
    lsum += e;
  }
  #pragma unroll
  for (int o = 32; o >= 1; o >>= 1) lsum += __shfl_xor(lsum, o);
  if ((t & 63) == 0) red[t >> 6] = lsum;
  __syncthreads();
  float inv = 1.0f / (red[0] + red[1] + red[2] + red[3]);
  for (int i = 0; i < 8; ++i) {
    int s = t + i * 256;
    out[(size_t)65536 + b * S_ + s] = sc[s] * inv;
  }
}

// ---------------- kernel 5: context partials ----------------
__global__ void k_ctx_partial(const float* __restrict__ keys, const float* __restrict__ wts,
                              float* __restrict__ cp) {
  int b = blockIdx.x;
  int dc = blockIdx.y;
  int scn = blockIdx.z;
  int t = threadIdx.x;
  __shared__ float wl[256];
  int s0 = scn * 256;
  wl[t] = wts[b * S_ + s0 + t];
  __syncthreads();
  int d = dc * 1024 + t * 4;
  f32x4 acc = {};
  #pragma unroll 4
  for (int i = 0; i < 256; ++i) {
    int s = s0 + i;
    f32x4 kv = *(const f32x4*)(keys + ((size_t)s * B_ + b) * D2_ + d);
    acc += kv * wl[i];
  }
  *(f32x4*)(cp + ((size_t)scn * B_ + b) * D2_ + d) = acc;
}

// ---------------- kernel 6: reduce context partials ----------------
__global__ void k_ctx_reduce(const float* __restrict__ cp, float* __restrict__ out) {
  int i = blockIdx.x * 256 + threadIdx.x;
  float s = 0.f;
  #pragma unroll
  for (int j = 0; j < 8; ++j) s += cp[(size_t)j * 65536 + i];
  out[i] = s;
}

extern "C" void kernel_launch(void* const* d_in, const int* in_sizes, int n_in,
                              void* d_out, int out_size, void* d_ws, size_t ws_size,
                              hipStream_t stream) {
  const float* query = (const float*)d_in[0];
  const float* keys  = (const float*)d_in[1];
  const float* Wa_w  = (const float*)d_in[2];
  const float* Wa_b  = (const float*)d_in[3];
  const float* Ua_w  = (const float*)d_in[4];
  const float* Ua_b  = (const float*)d_in[5];
  const float* Va_w  = (const float*)d_in[6];
  // Va_b (d_in[7]) intentionally unused: softmax is shift-invariant.
  float* out = (float*)d_out;
  char* ws = (char*)d_ws;

  const size_t KEYS_BF_BYTES = 268435456ull;  // 256 MiB
  const size_t TAIL = 11ull * 1024 * 1024;    // uab 4M + wqb 128K + sp 4M + cp 2M + pad
  bool big = ws_size >= KEYS_BF_BYTES + TAIL;

  if (big) {
    short* keys_bf = (short*)ws;
    char* base = ws + KEYS_BF_BYTES;
    short* uab_t = (short*)(base);
    float* wqb = (float*)(base + 4u * 1024 * 1024);
    float* sp  = (float*)(base + 4u * 1024 * 1024 + 128 * 1024);
    float* cp  = (float*)(base + 8u * 1024 * 1024 + 256 * 1024);

    hipLaunchKernelGGL(k_convert_ua, dim3(1024), dim3(256), 0, stream, Ua_w, uab_t);
    hipLaunchKernelGGL(k_convert_keys, dim3(65536), dim3(256), 0, stream, keys, keys_bf);
    hipLaunchKernelGGL(k_wq, dim3(32, 8), dim3(256), 0, stream, query, Wa_w, Wa_b, Ua_b, wqb);
    hipLaunchKernelGGL(k_gemm_score, dim3(1024), dim3(512), 0, stream, keys_bf, uab_t, wqb, Va_w, sp);
    hipLaunchKernelGGL(k_softmax, dim3(32), dim3(256), 0, stream, sp, out);
    hipLaunchKernelGGL(k_ctx_partial, dim3(32, 2, 8), dim3(256), 0, stream, keys, out + 65536, cp);
    hipLaunchKernelGGL(k_ctx_reduce, dim3(256), dim3(256), 0, stream, cp, out);
  } else {
    short* uab_t = (short*)(ws);
    float* wqb = (float*)(ws + 4u * 1024 * 1024);
    float* sp  = (float*)(ws + 4u * 1024 * 1024 + 128 * 1024);
    float* cp  = (float*)(ws + 8u * 1024 * 1024 + 256 * 1024);

    hipLaunchKernelGGL(k_convert_ua, dim3(1024), dim3(256), 0, stream, Ua_w, uab_t);
    hipLaunchKernelGGL(k_wq, dim3(32, 8), dim3(256), 0, stream, query, Wa_w, Wa_b, Ua_b, wqb);
    hipLaunchKernelGGL(k_gemm_rs, dim3(1024), dim3(512), 0, stream, keys, uab_t, wqb, Va_w, sp);
    hipLaunchKernelGGL(k_softmax, dim3(32), dim3(256), 0, stream, sp, out);
    hipLaunchKernelGGL(k_ctx_partial, dim3(32, 2, 8), dim3(256), 0, stream, keys, out + 65536, cp);
    hipLaunchKernelGGL(k_ctx_reduce, dim3(256), dim3(256), 0, stream, cp, out);
  }
}